// Round 1
// baseline (515.477 us; speedup 1.0000x reference)
//
#include <hip/hip_runtime.h>

// Problem constants (match reference)
#define BV    8
#define CV    16
#define NXV   512
#define NYV   512
#define NV    16384
#define NRES  90
#define NHV   5
#define TPB   256
#define CPERT 4   // channels per thread

#if __has_builtin(__builtin_amdgcn_exp2f)
#define EXP2 __builtin_amdgcn_exp2f
#else
#define EXP2 exp2f
#endif

__global__ __launch_bounds__(TPB, 4) void nu_grid_sampler_kernel(
    const float* __restrict__ x,       // [B,C,NX,NY]
    const float* __restrict__ coords,  // [B,N,2]
    const float* __restrict__ s_ptr,   // [1]
    const float* __restrict__ offn,    // [NRES] pixel_offset_normal
    const float* __restrict__ offi,    // [NHV]  pixel_offset_indices
    float* __restrict__ out)           // [B,C,N]
{
    const int n  = blockIdx.x * TPB + threadIdx.x;
    const int c0 = blockIdx.y * CPERT;
    const int b  = blockIdx.z;

    // coords[...,1] -> x-axis (rows, nx), coords[...,0] -> y-axis (cols, ny)
    const float2 cd = *(const float2*)(coords + ((size_t)b * NV + n) * 2);
    const float px  = cd.y * (float)(NXV - 1);
    const float py  = cd.x * (float)(NYV - 1);
    const float rpx = rintf(px);   // v_rndne: round-half-even == jnp.round
    const float rpy = rintf(py);

    const float s = s_ptr[0];
    const float k = -0.72134752044448169f / (s * s);  // -0.5*log2(e)/s^2
    // (the 1/(s*sqrt(2pi)) factor cancels in the w2d normalization)

    // --- gaussian bin weights: 90 sub-samples -> 5 bins per axis ---
    float wx[NHV], wy[NHV];
    float sx = 0.f, sy = 0.f;
    #pragma unroll
    for (int h = 0; h < NHV; ++h) {
        float ax = 0.f, ay = 0.f;
        #pragma unroll 6
        for (int t = 0; t < NRES / NHV; ++t) {
            const float off = offn[h * (NRES / NHV) + t];
            // clip(rp - off, 0, nx) on BOTH axes (faithful to reference)
            const float vx = fminf(fmaxf(rpx - off, 0.f), (float)NXV);
            const float vy = fminf(fmaxf(rpy - off, 0.f), (float)NXV);
            const float dx = vx - px;
            const float dy = vy - py;
            ax += EXP2(k * dx * dx);
            ay += EXP2(k * dy * dy);
        }
        wx[h] = ax; wy[h] = ay;
        sx += ax;  sy += ay;
    }
    const float inv = 1.0f / (sx * sy);  // w2d.sum() == (sum wx)*(sum wy)

    // --- integer neighborhood indices (clamped 0..nx-1 on both axes) ---
    int ix[NHV], iy[NHV];
    #pragma unroll
    for (int h = 0; h < NHV; ++h) {
        const float fo = offi[h];
        ix[h] = (int)fminf(fmaxf(rintf(rpx - fo), 0.f), (float)(NXV - 1));
        iy[h] = (int)fminf(fmaxf(rintf(rpy - fo), 0.f), (float)(NXV - 1));
    }

    // --- weighted 5x5 gather over CPERT channels ---
    const float* xb = x + (((size_t)b * CV + c0) * NXV) * (size_t)NYV;
    float acc[CPERT];
    #pragma unroll
    for (int q = 0; q < CPERT; ++q) acc[q] = 0.f;

    #pragma unroll
    for (int i = 0; i < NHV; ++i) {
        const float* rp = xb + (size_t)ix[i] * NYV;
        #pragma unroll
        for (int j = 0; j < NHV; ++j) {
            const float w  = wx[i] * wy[j];
            const int col  = iy[j];
            #pragma unroll
            for (int q = 0; q < CPERT; ++q)
                acc[q] += rp[(size_t)q * NXV * NYV + col] * w;
        }
    }

    #pragma unroll
    for (int q = 0; q < CPERT; ++q)
        out[((size_t)b * CV + (size_t)(c0 + q)) * NV + n] = acc[q] * inv;
}

extern "C" void kernel_launch(void* const* d_in, const int* in_sizes, int n_in,
                              void* d_out, int out_size, void* d_ws, size_t ws_size,
                              hipStream_t stream) {
    const float* x      = (const float*)d_in[0];
    const float* coords = (const float*)d_in[1];
    const float* s_ptr  = (const float*)d_in[2];
    const float* offn   = (const float*)d_in[3];
    const float* offi   = (const float*)d_in[4];
    float* out = (float*)d_out;

    dim3 grid(NV / TPB, CV / CPERT, BV);
    dim3 block(TPB);
    nu_grid_sampler_kernel<<<grid, block, 0, stream>>>(x, coords, s_ptr, offn, offi, out);
}

// Round 2
// 357.432 us; speedup vs baseline: 1.4422x; 1.4422x over previous
//
#include <hip/hip_runtime.h>

// Problem constants (match reference)
#define BV    8
#define CV    16
#define NXV   512
#define NYV   512
#define NV    16384
#define NRES  90
#define NHV   5
#define TPB   256
#define CPERT 4                     // channels per thread in gather kernel

#define NPTS  (BV * NV)             // 131072 points
#define TSH   3                     // 8x8-pixel tiles
#define TDIM  (NXV >> TSH)          // 64 tiles per axis
#define NBUCKB (TDIM * TDIM)        // 4096 buckets per batch
#define NBUCK  (BV * NBUCKB)        // 32768 buckets total
#define SCANT 1024                  // scan block size

#if __has_builtin(__builtin_amdgcn_exp2f)
#define EXP2 __builtin_amdgcn_exp2f
#else
#define EXP2 exp2f
#endif

// ---------------- kernel Z: zero bucket counts ----------------
__global__ void zero_counts_kernel(int* __restrict__ counts) {
    int i = blockIdx.x * blockDim.x + threadIdx.x;
    if (i < NBUCK) counts[i] = 0;
}

// ---------------- kernel A: histogram + keys ----------------
__global__ __launch_bounds__(TPB) void bucket_count_kernel(
    const float* __restrict__ coords, int* __restrict__ counts,
    int* __restrict__ keys)
{
    const int i = blockIdx.x * TPB + threadIdx.x;   // i = b*NV + n
    const float2 cd = *(const float2*)(coords + (size_t)i * 2);
    const float rpx = rintf(cd.y * (float)(NXV - 1));
    const float rpy = rintf(cd.x * (float)(NYV - 1));
    const unsigned tx = ((unsigned)(int)rpx) >> TSH;   // 0..63
    const unsigned ty = ((unsigned)(int)rpy) >> TSH;
    unsigned m = 0;
    #pragma unroll
    for (int k = 0; k < 6; ++k)
        m |= (((tx >> k) & 1u) << (2 * k)) | (((ty >> k) & 1u) << (2 * k + 1));
    const int key = (i >> 14) * NBUCKB + (int)m;       // b*4096 + morton
    keys[i] = key;
    atomicAdd(&counts[key], 1);
}

// ---------------- kernel B: exclusive prefix scan (single block) ----------------
__global__ __launch_bounds__(SCANT) void scan_kernel(
    const int* __restrict__ counts, int* __restrict__ cursors)
{
    __shared__ int sm[SCANT];
    const int tid = threadIdx.x;
    int carry = 0;
    for (int c = 0; c < NBUCK / SCANT; ++c) {
        const int idx = c * SCANT + tid;
        const int v = counts[idx];
        sm[tid] = v;
        __syncthreads();
        // Hillis-Steele inclusive scan
        for (int off = 1; off < SCANT; off <<= 1) {
            int t = sm[tid];
            if (tid >= off) t += sm[tid - off];
            __syncthreads();
            sm[tid] = t;
            __syncthreads();
        }
        const int incl = sm[tid];
        cursors[idx] = carry + incl - v;   // exclusive
        __syncthreads();
        carry += sm[SCANT - 1];
        __syncthreads();
    }
}

// ---------------- kernel C: scatter sorted order ----------------
__global__ __launch_bounds__(TPB) void scatter_kernel(
    const int* __restrict__ keys, int* __restrict__ cursors,
    int* __restrict__ order)
{
    const int i = blockIdx.x * TPB + threadIdx.x;
    const int pos = atomicAdd(&cursors[keys[i]], 1);
    order[pos] = i;
}

// ---------------- kernel D: main weighted gather, sorted order ----------------
__global__ __launch_bounds__(TPB, 4) void nu_grid_sampler_kernel(
    const float* __restrict__ x,       // [B,C,NX,NY]
    const float* __restrict__ coords,  // [B,N,2]
    const float* __restrict__ s_ptr,   // [1]
    const float* __restrict__ offn,    // [NRES]
    const float* __restrict__ offi,    // [NHV]
    const int* __restrict__ order,     // [NPTS] sorted point ids
    float* __restrict__ out)           // [B,C,N]
{
    // XCD-chunk swizzle: give each XCD a contiguous chunk of sorted points.
    const int nwg = NPTS / TPB;                       // 512 (divisible by 8)
    const int bid = blockIdx.x;
    const int swz = (bid & 7) * (nwg / 8) + (bid >> 3);
    const int p   = swz * TPB + threadIdx.x;

    const int i = order[p];           // b*NV + n
    const int b = i >> 14;
    const int n = i & (NV - 1);
    const int c0 = blockIdx.y * CPERT;

    const float2 cd = *(const float2*)(coords + (size_t)i * 2);
    const float px  = cd.y * (float)(NXV - 1);
    const float py  = cd.x * (float)(NYV - 1);
    const float rpx = rintf(px);      // round-half-even == jnp.round
    const float rpy = rintf(py);

    const float s = s_ptr[0];
    const float k = -0.72134752044448169f / (s * s);  // -0.5*log2(e)/s^2
    // (1/(s*sqrt(2pi)) cancels in normalization)

    float wx[NHV], wy[NHV];
    float sx = 0.f, sy = 0.f;
    #pragma unroll
    for (int h = 0; h < NHV; ++h) {
        float ax = 0.f, ay = 0.f;
        #pragma unroll 6
        for (int t = 0; t < NRES / NHV; ++t) {
            const float off = offn[h * (NRES / NHV) + t];
            const float vx = fminf(fmaxf(rpx - off, 0.f), (float)NXV);
            const float vy = fminf(fmaxf(rpy - off, 0.f), (float)NXV);
            const float dx = vx - px;
            const float dy = vy - py;
            ax += EXP2(k * dx * dx);
            ay += EXP2(k * dy * dy);
        }
        wx[h] = ax; wy[h] = ay;
        sx += ax;  sy += ay;
    }
    const float inv = 1.0f / (sx * sy);

    int ix[NHV], iy[NHV];
    #pragma unroll
    for (int h = 0; h < NHV; ++h) {
        const float fo = offi[h];
        ix[h] = (int)fminf(fmaxf(rintf(rpx - fo), 0.f), (float)(NXV - 1));
        iy[h] = (int)fminf(fmaxf(rintf(rpy - fo), 0.f), (float)(NXV - 1));
    }

    const float* xb = x + (((size_t)b * CV + c0) * NXV) * (size_t)NYV;
    float acc[CPERT];
    #pragma unroll
    for (int q = 0; q < CPERT; ++q) acc[q] = 0.f;

    #pragma unroll
    for (int ii = 0; ii < NHV; ++ii) {
        const float* rp = xb + (size_t)ix[ii] * NYV;
        #pragma unroll
        for (int j = 0; j < NHV; ++j) {
            const float w  = wx[ii] * wy[j];
            const int col  = iy[j];
            #pragma unroll
            for (int q = 0; q < CPERT; ++q)
                acc[q] += rp[(size_t)q * NXV * NYV + col] * w;
        }
    }

    #pragma unroll
    for (int q = 0; q < CPERT; ++q)
        out[((size_t)b * CV + (size_t)(c0 + q)) * NV + n] = acc[q] * inv;
}

extern "C" void kernel_launch(void* const* d_in, const int* in_sizes, int n_in,
                              void* d_out, int out_size, void* d_ws, size_t ws_size,
                              hipStream_t stream) {
    const float* x      = (const float*)d_in[0];
    const float* coords = (const float*)d_in[1];
    const float* s_ptr  = (const float*)d_in[2];
    const float* offn   = (const float*)d_in[3];
    const float* offi   = (const float*)d_in[4];
    float* out = (float*)d_out;

    // workspace layout: counts | cursors | keys | order  (all int32)
    int* counts  = (int*)d_ws;
    int* cursors = counts + NBUCK;
    int* keys    = cursors + NBUCK;
    int* order   = keys + NPTS;
    // needs (2*NBUCK + 2*NPTS)*4 = 1.31 MB of ws

    zero_counts_kernel<<<dim3(NBUCK / TPB), dim3(TPB), 0, stream>>>(counts);
    bucket_count_kernel<<<dim3(NPTS / TPB), dim3(TPB), 0, stream>>>(coords, counts, keys);
    scan_kernel<<<dim3(1), dim3(SCANT), 0, stream>>>(counts, cursors);
    scatter_kernel<<<dim3(NPTS / TPB), dim3(TPB), 0, stream>>>(keys, cursors, order);

    dim3 grid(NPTS / TPB, CV / CPERT, 1);
    nu_grid_sampler_kernel<<<grid, dim3(TPB), 0, stream>>>(
        x, coords, s_ptr, offn, offi, order, out);
}

// Round 3
// 264.049 us; speedup vs baseline: 1.9522x; 1.3537x over previous
//
#include <hip/hip_runtime.h>

// Problem constants (match reference)
#define BV    8
#define CV    16
#define NXV   512
#define NYV   512
#define NV    16384
#define NRES  90
#define NHV   5
#define TPB   256

#define NPTS  (BV * NV)             // 131072 points
#define TSH   3                     // 8x8-pixel tiles
#define TDIM  (NXV >> TSH)          // 64 tiles per axis
#define NBUCKB (TDIM * TDIM)        // 4096 buckets per batch
#define NBUCK  (BV * NBUCKB)        // 32768 buckets total
#define SCANT 1024
#define SPT   (NBUCK / SCANT)       // 32 elements per scan thread

#if __has_builtin(__builtin_amdgcn_exp2f)
#define EXP2 __builtin_amdgcn_exp2f
#else
#define EXP2 exp2f
#endif

// ---------------- kernel Z: zero bucket counts ----------------
__global__ void zero_counts_kernel(int* __restrict__ counts) {
    int i = blockIdx.x * blockDim.x + threadIdx.x;
    if (i < NBUCK) counts[i] = 0;
}

// ---------------- kernel A: histogram + keys ----------------
__global__ __launch_bounds__(TPB) void bucket_count_kernel(
    const float* __restrict__ coords, int* __restrict__ counts,
    int* __restrict__ keys)
{
    const int i = blockIdx.x * TPB + threadIdx.x;   // i = b*NV + n
    const float2 cd = *(const float2*)(coords + (size_t)i * 2);
    const float rpx = rintf(cd.y * (float)(NXV - 1));
    const float rpy = rintf(cd.x * (float)(NYV - 1));
    const unsigned tx = ((unsigned)(int)rpx) >> TSH;   // 0..63
    const unsigned ty = ((unsigned)(int)rpy) >> TSH;
    unsigned m = 0;
    #pragma unroll
    for (int k = 0; k < 6; ++k)
        m |= (((tx >> k) & 1u) << (2 * k)) | (((ty >> k) & 1u) << (2 * k + 1));
    const int key = (i >> 14) * NBUCKB + (int)m;       // b*4096 + morton
    keys[i] = key;
    atomicAdd(&counts[key], 1);
}

// ---------------- kernel B: exclusive prefix scan, one pass ----------------
// 1024 threads x 32 serial elements + one LDS scan of the 1024 partials.
__global__ __launch_bounds__(SCANT) void scan_kernel(
    const int* __restrict__ counts, int* __restrict__ cursors)
{
    __shared__ int sm[SCANT];
    const int tid  = threadIdx.x;
    const int base = tid * SPT;

    int v[SPT];
    int run = 0;
    #pragma unroll
    for (int k = 0; k < SPT; ++k) {
        v[k] = run;                       // exclusive within thread
        run += counts[base + k];
    }
    sm[tid] = run;
    __syncthreads();
    #pragma unroll
    for (int off = 1; off < SCANT; off <<= 1) {
        int t = sm[tid];
        if (tid >= off) t += sm[tid - off];
        __syncthreads();
        sm[tid] = t;
        __syncthreads();
    }
    const int tbase = sm[tid] - run;      // exclusive prefix of thread totals
    #pragma unroll
    for (int k = 0; k < SPT; ++k)
        cursors[base + k] = tbase + v[k];
}

// ---------------- kernel C: scatter sorted order ----------------
__global__ __launch_bounds__(TPB) void scatter_kernel(
    const int* __restrict__ keys, int* __restrict__ cursors,
    int* __restrict__ order)
{
    const int i = blockIdx.x * TPB + threadIdx.x;
    const int pos = atomicAdd(&cursors[keys[i]], 1);
    order[pos] = i;
}

// ---------------- kernel W: per-point weights / offsets ----------------
// Per sorted point p: 8-slot column weights (inv folded in, clamp duplicates
// folded in), 5 row weights, 5 row byte-offsets (col-base aligned to float4),
// and the original point id.
__global__ __launch_bounds__(TPB) void weights_kernel(
    const float* __restrict__ coords,
    const float* __restrict__ s_ptr,
    const float* __restrict__ offn,    // [NRES]
    const float* __restrict__ offi,    // [NHV]
    const int*   __restrict__ order,
    float4* __restrict__ w8a, float4* __restrict__ w8b,
    float4* __restrict__ wx4, float* __restrict__ wx1,
    int4*   __restrict__ off4, int* __restrict__ off1,
    int*    __restrict__ idx)
{
    const int p = blockIdx.x * TPB + threadIdx.x;
    const int i = order[p];

    const float2 cd = *(const float2*)(coords + (size_t)i * 2);
    const float px  = cd.y * (float)(NXV - 1);
    const float py  = cd.x * (float)(NYV - 1);
    const float rpx = rintf(px);          // round-half-even == jnp.round
    const float rpy = rintf(py);

    const float s = s_ptr[0];
    const float k = -0.72134752044448169f / (s * s);  // -0.5*log2(e)/s^2
    // (1/(s*sqrt(2pi)) cancels in normalization)

    float wx[NHV], wy[NHV];
    float sx = 0.f, sy = 0.f;
    #pragma unroll
    for (int h = 0; h < NHV; ++h) {
        float ax = 0.f, ay = 0.f;
        #pragma unroll 6
        for (int t = 0; t < NRES / NHV; ++t) {
            const float off = offn[h * (NRES / NHV) + t];
            const float vx = fminf(fmaxf(rpx - off, 0.f), (float)NXV);
            const float vy = fminf(fmaxf(rpy - off, 0.f), (float)NXV);
            const float dx = vx - px;
            const float dy = vy - py;
            ax += EXP2(k * dx * dx);
            ay += EXP2(k * dy * dy);
        }
        wx[h] = ax; wy[h] = ay;
        sx += ax;  sy += ay;
    }
    const float inv = 1.0f / (sx * sy);   // w2d.sum() == (sum wx)*(sum wy)

    int ix[NHV], iy[NHV];
    #pragma unroll
    for (int h = 0; h < NHV; ++h) {
        const float fo = offi[h];
        ix[h] = (int)fminf(fmaxf(rintf(rpx - fo), 0.f), (float)(NXV - 1));
        iy[h] = (int)fminf(fmaxf(rintf(rpy - fo), 0.f), (float)(NXV - 1));
    }

    // column base aligned to float4; all 5 clamped cols live in [a, a+8)
    const int a = min(iy[NHV - 1] & ~3, NYV - 8);

    // scatter wy*inv into 8 slots (clamp duplicates accumulate)
    float w8[8];
    #pragma unroll
    for (int kk = 0; kk < 8; ++kk) {
        float w = 0.f;
        #pragma unroll
        for (int j = 0; j < NHV; ++j)
            w += (iy[j] - a == kk) ? wy[j] * inv : 0.f;
        w8[kk] = w;
    }

    w8a[p] = make_float4(w8[0], w8[1], w8[2], w8[3]);
    w8b[p] = make_float4(w8[4], w8[5], w8[6], w8[7]);
    wx4[p] = make_float4(wx[0], wx[1], wx[2], wx[3]);
    wx1[p] = wx[4];
    off4[p] = make_int4((ix[0] * NYV + a) * 4, (ix[1] * NYV + a) * 4,
                        (ix[2] * NYV + a) * 4, (ix[3] * NYV + a) * 4);
    off1[p] = (ix[4] * NYV + a) * 4;
    idx[p]  = i;
}

// ---------------- kernel G: vectorized weighted gather ----------------
__global__ __launch_bounds__(TPB) void gather_kernel(
    const float* __restrict__ x,
    const float4* __restrict__ w8a, const float4* __restrict__ w8b,
    const float4* __restrict__ wx4, const float* __restrict__ wx1,
    const int4*   __restrict__ off4, const int* __restrict__ off1,
    const int*    __restrict__ idx,
    float* __restrict__ out)
{
    // XCD-chunk swizzle on point-chunk dimension
    const int nwg = NPTS / TPB;                       // 512
    const int bid = blockIdx.x;
    const int swz = (bid & 7) * (nwg / 8) + (bid >> 3);
    const int p   = swz * TPB + threadIdx.x;
    const int c   = blockIdx.y;

    const float4 wa = w8a[p];
    const float4 wb = w8b[p];
    const float4 wr = wx4[p];
    const float  we = wx1[p];
    const int4   o4 = off4[p];
    const int    oe = off1[p];
    const int    i  = idx[p];
    const int    b  = i >> 14;
    const int    n  = i & (NV - 1);

    const char* base = (const char*)x + ((size_t)(b * CV + c) << 20); // plane = 1 MB

    float acc = 0.f;
#define ROW(OFF, WROW) {                                                    \
        const float4* rp = (const float4*)(base + (size_t)(unsigned)(OFF)); \
        const float4 va = rp[0];                                            \
        const float4 vb = rp[1];                                            \
        const float rs = va.x * wa.x + va.y * wa.y + va.z * wa.z +          \
                         va.w * wa.w + vb.x * wb.x + vb.y * wb.y +          \
                         vb.z * wb.z + vb.w * wb.w;                         \
        acc = fmaf(WROW, rs, acc); }

    ROW(o4.x, wr.x)
    ROW(o4.y, wr.y)
    ROW(o4.z, wr.z)
    ROW(o4.w, wr.w)
    ROW(oe,   we)
#undef ROW

    out[(((size_t)(b * CV + c)) << 14) + n] = acc;
}

extern "C" void kernel_launch(void* const* d_in, const int* in_sizes, int n_in,
                              void* d_out, int out_size, void* d_ws, size_t ws_size,
                              hipStream_t stream) {
    const float* x      = (const float*)d_in[0];
    const float* coords = (const float*)d_in[1];
    const float* s_ptr  = (const float*)d_in[2];
    const float* offn   = (const float*)d_in[3];
    const float* offi   = (const float*)d_in[4];
    float* out = (float*)d_out;

    // workspace layout (16B-aligned arrays first); total ~11.2 MB
    char* w = (char*)d_ws;
    float4* w8a  = (float4*)w;  w += (size_t)NPTS * 16;
    float4* w8b  = (float4*)w;  w += (size_t)NPTS * 16;
    float4* wx4  = (float4*)w;  w += (size_t)NPTS * 16;
    int4*   off4 = (int4*)w;    w += (size_t)NPTS * 16;
    float*  wx1  = (float*)w;   w += (size_t)NPTS * 4;
    int*    off1 = (int*)w;     w += (size_t)NPTS * 4;
    int*    idx  = (int*)w;     w += (size_t)NPTS * 4;
    int*    counts  = (int*)w;  w += (size_t)NBUCK * 4;
    int*    cursors = (int*)w;  w += (size_t)NBUCK * 4;
    int*    keys    = (int*)w;  w += (size_t)NPTS * 4;
    int*    order   = (int*)w;

    zero_counts_kernel<<<dim3(NBUCK / TPB), dim3(TPB), 0, stream>>>(counts);
    bucket_count_kernel<<<dim3(NPTS / TPB), dim3(TPB), 0, stream>>>(coords, counts, keys);
    scan_kernel<<<dim3(1), dim3(SCANT), 0, stream>>>(counts, cursors);
    scatter_kernel<<<dim3(NPTS / TPB), dim3(TPB), 0, stream>>>(keys, cursors, order);
    weights_kernel<<<dim3(NPTS / TPB), dim3(TPB), 0, stream>>>(
        coords, s_ptr, offn, offi, order, w8a, w8b, wx4, wx1, off4, off1, idx);

    dim3 grid(NPTS / TPB, CV, 1);
    gather_kernel<<<grid, dim3(TPB), 0, stream>>>(
        x, w8a, w8b, wx4, wx1, off4, off1, idx, out);
}